// Round 17
// baseline (824.219 us; speedup 1.0000x reference)
//
#include <hip/hip_runtime.h>
#include <hip/hip_bf16.h>

#define NUM_HEADS 4
#define HD 256
#define QD 256
#define VD 256
#define B_SZ 32
#define N_NODES 8192
#define NEG_SLOPE 0.2f
#define CH 16
#define NCH 32
#define KSTRIDE 1040

typedef short bf16x8 __attribute__((ext_vector_type(8)));
typedef float f32x4 __attribute__((ext_vector_type(4)));

static __device__ __forceinline__ unsigned short f2bf(float f) {
    __hip_bfloat16 h = __float2bfloat16(f);
    return *reinterpret_cast<unsigned short*>(&h);
}

static __device__ __forceinline__ void gload_lds16(const float* g, void* l) {
    __builtin_amdgcn_global_load_lds(
        (const __attribute__((address_space(1))) void*)g,
        (__attribute__((address_space(3))) void*)l, 16, 0, 0);
}

// ---------------------------------------------------------------------------
// Kernel 1: prep (unchanged)
// ---------------------------------------------------------------------------
__global__ __launch_bounds__(256)
void prep_kernel(const float* __restrict__ query,
                 const float* __restrict__ Wq,
                 const float* __restrict__ bq,
                 unsigned short* __restrict__ WqP,
                 float* __restrict__ hqb) {
    int blk = blockIdx.x;
    int tid = threadIdx.x;
    if (blk < 32) {
        int b = blk, col = tid;
        float acc = 2.0f * bq[col];
#pragma unroll 16
        for (int k = 0; k < QD; ++k)
            acc += query[b * QD + k] * Wq[k * HD + col];
        hqb[b * HD + col] = acc;
    } else {
        int idx = blk - 32;
        int kstep = idx >> 2, g = idx & 3;
        int col = tid;
        int h = col >> 6, ct = (col >> 4) & 3, col16 = col & 15;
        unsigned short v[8];
#pragma unroll
        for (int j = 0; j < 8; ++j)
            v[j] = f2bf(Wq[(kstep * 32 + g * 8 + j) * HD + col]);
        *reinterpret_cast<uint4*>(
            WqP + kstep * 8192 + h * 2048 + ct * 512 + (g * 16 + col16) * 8) =
            *reinterpret_cast<uint4*>(v);
    }
}

// ---------------------------------------------------------------------------
// Kernel 2: production fused (R15 verbatim, passed @132 µs)
// ---------------------------------------------------------------------------
__global__ __launch_bounds__(256, 2)
void fused_kernel(const float* __restrict__ key,
                  const float* __restrict__ value,
                  const unsigned short* __restrict__ WqP,
                  const float* __restrict__ hqb,
                  const float* __restrict__ avec,
                  float* __restrict__ s,
                  float* __restrict__ p_part,
                  float* __restrict__ pml) {
    __shared__ __align__(16) char smem[2 * (CH * KSTRIDE) + 2 * (CH * 1024)];

    char* kb0 = smem;
    char* kb1 = smem + CH * KSTRIDE;
    char* vb0 = smem + 2 * CH * KSTRIDE;
    char* vb1 = vb0 + CH * 1024;

    int bid = blockIdx.x;
    int b = bid >> 4, strip = bid & 15;
    int tid = threadIdx.x;
    int w = tid >> 6, lane = tid & 63;
    int col16 = lane & 15, g = (lane >> 4) & 3;
    int h = w;
    int rowbase0 = strip * 512;

    bf16x8 bfr[8][4];
    {
        const unsigned short* wp0 = WqP + h * 2048 + (g * 16 + col16) * 8;
#pragma unroll
        for (int ks = 0; ks < 8; ++ks)
#pragma unroll
            for (int ct = 0; ct < 4; ++ct)
                bfr[ks][ct] = *reinterpret_cast<const bf16x8*>(wp0 + ks * 8192 + ct * 512);
    }
    float av16[4][4], hq16[4][4];
#pragma unroll
    for (int ct = 0; ct < 4; ++ct)
#pragma unroll
        for (int r = 0; r < 4; ++r) {
            int d = ct * 16 + g * 4 + r;
            av16[ct][r] = avec[d];
            hq16[ct][r] = hqb[b * HD + h * 64 + d];
        }

    float mr = -1e30f, lr = 0.f;
    f32x4 pa = (f32x4){0.f, 0.f, 0.f, 0.f};

    {
        int rb = rowbase0;
#pragma unroll
        for (int r = 0; r < 4; ++r) {
            int lr_ = w * 4 + r;
            gload_lds16(key + ((size_t)(b * N_NODES + rb + lr_)) * QD + lane * 4,
                        kb0 + lr_ * KSTRIDE);
            gload_lds16(value + ((size_t)(b * N_NODES + rb + lr_)) * VD + lane * 4,
                        vb0 + lr_ * 1024);
        }
    }

    for (int t = 0; t < NCH; ++t) {
        __builtin_amdgcn_s_barrier();
        if (t + 1 < NCH) {
            char* kbn = ((t + 1) & 1) ? kb1 : kb0;
            char* vbn = ((t + 1) & 1) ? vb1 : vb0;
            int rb = rowbase0 + (t + 1) * CH;
#pragma unroll
            for (int r = 0; r < 4; ++r) {
                int lr_ = w * 4 + r;
                gload_lds16(key + ((size_t)(b * N_NODES + rb + lr_)) * QD + lane * 4,
                            kbn + lr_ * KSTRIDE);
            }
#pragma unroll
            for (int r = 0; r < 4; ++r) {
                int lr_ = w * 4 + r;
                gload_lds16(value + ((size_t)(b * N_NODES + rb + lr_)) * VD + lane * 4,
                            vbn + lr_ * 1024);
            }
            asm volatile("s_waitcnt vmcnt(8)" ::: "memory");
        } else {
            asm volatile("s_waitcnt vmcnt(0)" ::: "memory");
        }
        __builtin_amdgcn_s_barrier();
        __builtin_amdgcn_sched_barrier(0);

        const char* kb = (t & 1) ? kb1 : kb0;
        const char* vb = (t & 1) ? vb1 : vb0;
        int n0c = rowbase0 + t * CH;

        bf16x8 a[8];
#pragma unroll
        for (int ks = 0; ks < 8; ++ks) {
            f32x4 lo = *reinterpret_cast<const f32x4*>(kb + col16 * KSTRIDE + ks * 128 + g * 32);
            f32x4 hi = *reinterpret_cast<const f32x4*>(kb + col16 * KSTRIDE + ks * 128 + g * 32 + 16);
            unsigned int u0, u1, u2, u3;
            asm("v_cvt_pk_bf16_f32 %0, %1, %2" : "=v"(u0) : "v"(lo[0]), "v"(lo[1]));
            asm("v_cvt_pk_bf16_f32 %0, %1, %2" : "=v"(u1) : "v"(lo[2]), "v"(lo[3]));
            asm("v_cvt_pk_bf16_f32 %0, %1, %2" : "=v"(u2) : "v"(hi[0]), "v"(hi[1]));
            asm("v_cvt_pk_bf16_f32 %0, %1, %2" : "=v"(u3) : "v"(hi[2]), "v"(hi[3]));
            uint4 tt = {u0, u1, u2, u3};
            a[ks] = *reinterpret_cast<bf16x8*>(&tt);
        }

        f32x4 acc[4];
#pragma unroll
        for (int ct = 0; ct < 4; ++ct) acc[ct] = (f32x4){0.f, 0.f, 0.f, 0.f};
#pragma unroll
        for (int ks = 0; ks < 8; ++ks)
#pragma unroll
            for (int ct = 0; ct < 4; ++ct)
                acc[ct] = __builtin_amdgcn_mfma_f32_16x16x32_bf16(bfr[ks][ct], a[ks], acc[ct], 0, 0, 0);

        float dot = 0.f;
#pragma unroll
        for (int ct = 0; ct < 4; ++ct) {
#pragma unroll
            for (int r = 0; r < 4; ++r) {
                float pre = acc[ct][r] + hq16[ct][r];
                float tv = fmaxf(pre, NEG_SLOPE * pre);
                dot += av16[ct][r] * tv;
            }
        }
        dot += __shfl_xor(dot, 16, 64);
        dot += __shfl_xor(dot, 32, 64);

        if (lane < 16)
            s[((size_t)(b * NUM_HEADS + h)) * N_NODES + n0c + lane] = dot;

        float mc = dot;
        mc = fmaxf(mc, __shfl_xor(mc, 1, 64));
        mc = fmaxf(mc, __shfl_xor(mc, 2, 64));
        mc = fmaxf(mc, __shfl_xor(mc, 4, 64));
        mc = fmaxf(mc, __shfl_xor(mc, 8, 64));
        float mnew = fmaxf(mr, mc);
        float ep = __expf(dot - mnew);
        float lc = ep;
        lc += __shfl_xor(lc, 1, 64);
        lc += __shfl_xor(lc, 2, 64);
        lc += __shfl_xor(lc, 4, 64);
        lc += __shfl_xor(lc, 8, 64);
        float scf = __expf(mr - mnew);
        pa *= scf;
        lr = lr * scf + lc;
        mr = mnew;

#pragma unroll
        for (int n = 0; n < 16; ++n) {
            f32x4 v = *reinterpret_cast<const f32x4*>(vb + n * 1024 + lane * 16);
            float e = __shfl(ep, n, 64);
            pa += e * v;
        }
    }

    int slot = bid * 4 + w;
    *reinterpret_cast<f32x4*>(p_part + (size_t)slot * 256 + lane * 4) = pa;
    if (lane == 0) {
        pml[slot * 2] = mr;
        pml[slot * 2 + 1] = lr;
    }
}

// ---------------------------------------------------------------------------
// PROBE A: stream_probe — staging skeleton only, nch chunks (mod-32 rows).
// Identical barrier/vmcnt/gload structure; compute stubbed to 2 LDS reads.
// ---------------------------------------------------------------------------
__global__ __launch_bounds__(256, 2)
void stream_probe(const float* __restrict__ key,
                  const float* __restrict__ value,
                  float* __restrict__ scratch, int nch) {
    __shared__ __align__(16) char smem[2 * (CH * KSTRIDE) + 2 * (CH * 1024)];
    char* kb0 = smem;
    char* kb1 = smem + CH * KSTRIDE;
    char* vb0 = smem + 2 * CH * KSTRIDE;
    char* vb1 = vb0 + CH * 1024;

    int bid = blockIdx.x;
    int b = bid >> 4, strip = bid & 15;
    int tid = threadIdx.x;
    int w = tid >> 6, lane = tid & 63;
    int col16 = lane & 15, g = (lane >> 4) & 3;
    int rowbase0 = strip * 512;

    f32x4 pa = (f32x4){0.f, 0.f, 0.f, 0.f};

    {
#pragma unroll
        for (int r = 0; r < 4; ++r) {
            int lr_ = w * 4 + r;
            gload_lds16(key + ((size_t)(b * N_NODES + rowbase0 + lr_)) * QD + lane * 4,
                        kb0 + lr_ * KSTRIDE);
            gload_lds16(value + ((size_t)(b * N_NODES + rowbase0 + lr_)) * VD + lane * 4,
                        vb0 + lr_ * 1024);
        }
    }

    for (int t = 0; t < nch; ++t) {
        __builtin_amdgcn_s_barrier();
        if (t + 1 < nch) {
            char* kbn = ((t + 1) & 1) ? kb1 : kb0;
            char* vbn = ((t + 1) & 1) ? vb1 : vb0;
            int rb = rowbase0 + ((t + 1) & 31) * CH;
#pragma unroll
            for (int r = 0; r < 4; ++r) {
                int lr_ = w * 4 + r;
                gload_lds16(key + ((size_t)(b * N_NODES + rb + lr_)) * QD + lane * 4,
                            kbn + lr_ * KSTRIDE);
            }
#pragma unroll
            for (int r = 0; r < 4; ++r) {
                int lr_ = w * 4 + r;
                gload_lds16(value + ((size_t)(b * N_NODES + rb + lr_)) * VD + lane * 4,
                            vbn + lr_ * 1024);
            }
            asm volatile("s_waitcnt vmcnt(8)" ::: "memory");
        } else {
            asm volatile("s_waitcnt vmcnt(0)" ::: "memory");
        }
        __builtin_amdgcn_s_barrier();
        __builtin_amdgcn_sched_barrier(0);

        const char* kb = (t & 1) ? kb1 : kb0;
        const char* vb = (t & 1) ? vb1 : vb0;
        f32x4 kx = *reinterpret_cast<const f32x4*>(kb + col16 * KSTRIDE + g * 32);
        f32x4 vx = *reinterpret_cast<const f32x4*>(vb + col16 * 1024 + g * 16);
        pa += kx;
        pa += vx;
        asm volatile("" ::: "memory");
    }

    int slot = bid * 4 + w;
    *reinterpret_cast<f32x4*>(scratch + (size_t)slot * 256 + lane * 4) = pa;
}

// ---------------------------------------------------------------------------
// PROBE B: comp_probe — stage once, full compute loop (no in-loop staging).
// Same 2-barriers-per-iteration structure.
// ---------------------------------------------------------------------------
__global__ __launch_bounds__(256, 2)
void comp_probe(const float* __restrict__ key,
                const float* __restrict__ value,
                const unsigned short* __restrict__ WqP,
                const float* __restrict__ hqb,
                const float* __restrict__ avec,
                float* __restrict__ scratch,
                float* __restrict__ scratch2, int nch) {
    __shared__ __align__(16) char smem[2 * (CH * KSTRIDE) + 2 * (CH * 1024)];
    char* kb0 = smem;
    char* vb0 = smem + 2 * (CH * KSTRIDE);

    int bid = blockIdx.x;
    int b = bid >> 4, strip = bid & 15;
    int tid = threadIdx.x;
    int w = tid >> 6, lane = tid & 63;
    int col16 = lane & 15, g = (lane >> 4) & 3;
    int h = w;
    int rowbase0 = strip * 512;

    bf16x8 bfr[8][4];
    {
        const unsigned short* wp0 = WqP + h * 2048 + (g * 16 + col16) * 8;
#pragma unroll
        for (int ks = 0; ks < 8; ++ks)
#pragma unroll
            for (int ct = 0; ct < 4; ++ct)
                bfr[ks][ct] = *reinterpret_cast<const bf16x8*>(wp0 + ks * 8192 + ct * 512);
    }
    float av16[4][4], hq16[4][4];
#pragma unroll
    for (int ct = 0; ct < 4; ++ct)
#pragma unroll
        for (int r = 0; r < 4; ++r) {
            int d = ct * 16 + g * 4 + r;
            av16[ct][r] = avec[d];
            hq16[ct][r] = hqb[b * HD + h * 64 + d];
        }

    float mr = -1e30f, lr = 0.f;
    f32x4 pa = (f32x4){0.f, 0.f, 0.f, 0.f};

    {
#pragma unroll
        for (int r = 0; r < 4; ++r) {
            int lr_ = w * 4 + r;
            gload_lds16(key + ((size_t)(b * N_NODES + rowbase0 + lr_)) * QD + lane * 4,
                        kb0 + lr_ * KSTRIDE);
            gload_lds16(value + ((size_t)(b * N_NODES + rowbase0 + lr_)) * VD + lane * 4,
                        vb0 + lr_ * 1024);
        }
    }
    asm volatile("s_waitcnt vmcnt(0)" ::: "memory");
    __builtin_amdgcn_s_barrier();

    for (int t = 0; t < nch; ++t) {
        __builtin_amdgcn_s_barrier();
        __builtin_amdgcn_s_barrier();
        __builtin_amdgcn_sched_barrier(0);
        asm volatile("" ::: "memory");

        bf16x8 a[8];
#pragma unroll
        for (int ks = 0; ks < 8; ++ks) {
            f32x4 lo = *reinterpret_cast<const f32x4*>(kb0 + col16 * KSTRIDE + ks * 128 + g * 32);
            f32x4 hi = *reinterpret_cast<const f32x4*>(kb0 + col16 * KSTRIDE + ks * 128 + g * 32 + 16);
            unsigned int u0, u1, u2, u3;
            asm("v_cvt_pk_bf16_f32 %0, %1, %2" : "=v"(u0) : "v"(lo[0]), "v"(lo[1]));
            asm("v_cvt_pk_bf16_f32 %0, %1, %2" : "=v"(u1) : "v"(lo[2]), "v"(lo[3]));
            asm("v_cvt_pk_bf16_f32 %0, %1, %2" : "=v"(u2) : "v"(hi[0]), "v"(hi[1]));
            asm("v_cvt_pk_bf16_f32 %0, %1, %2" : "=v"(u3) : "v"(hi[2]), "v"(hi[3]));
            uint4 tt = {u0, u1, u2, u3};
            a[ks] = *reinterpret_cast<bf16x8*>(&tt);
        }

        f32x4 acc[4];
#pragma unroll
        for (int ct = 0; ct < 4; ++ct) acc[ct] = (f32x4){0.f, 0.f, 0.f, 0.f};
#pragma unroll
        for (int ks = 0; ks < 8; ++ks)
#pragma unroll
            for (int ct = 0; ct < 4; ++ct)
                acc[ct] = __builtin_amdgcn_mfma_f32_16x16x32_bf16(bfr[ks][ct], a[ks], acc[ct], 0, 0, 0);

        float dot = 0.f;
#pragma unroll
        for (int ct = 0; ct < 4; ++ct) {
#pragma unroll
            for (int r = 0; r < 4; ++r) {
                float pre = acc[ct][r] + hq16[ct][r];
                float tv = fmaxf(pre, NEG_SLOPE * pre);
                dot += av16[ct][r] * tv;
            }
        }
        dot += __shfl_xor(dot, 16, 64);
        dot += __shfl_xor(dot, 32, 64);

        float mc = dot;
        mc = fmaxf(mc, __shfl_xor(mc, 1, 64));
        mc = fmaxf(mc, __shfl_xor(mc, 2, 64));
        mc = fmaxf(mc, __shfl_xor(mc, 4, 64));
        mc = fmaxf(mc, __shfl_xor(mc, 8, 64));
        float mnew = fmaxf(mr, mc);
        float ep = __expf(dot - mnew);
        float lc = ep;
        lc += __shfl_xor(lc, 1, 64);
        lc += __shfl_xor(lc, 2, 64);
        lc += __shfl_xor(lc, 4, 64);
        lc += __shfl_xor(lc, 8, 64);
        float scf = __expf(mr - mnew);
        pa *= scf;
        lr = lr * scf + lc;
        mr = mnew;

#pragma unroll
        for (int n = 0; n < 16; ++n) {
            f32x4 v = *reinterpret_cast<const f32x4*>(vb0 + n * 1024 + lane * 16);
            float e = __shfl(ep, n, 64);
            pa += e * v;
        }
    }

    int slot = bid * 4 + w;
    *reinterpret_cast<f32x4*>(scratch + (size_t)slot * 256 + lane * 4) = pa;
    if (lane == 0) {
        scratch2[slot * 2] = mr;
        scratch2[slot * 2 + 1] = lr;
    }
}

// ---------------------------------------------------------------------------
// Kernel 3: final (unchanged)
// ---------------------------------------------------------------------------
__global__ __launch_bounds__(256)
void final_kernel(const float* __restrict__ p_part,
                  const float* __restrict__ pml,
                  const float* __restrict__ Wv,
                  const float* __restrict__ bv,
                  float* __restrict__ hout,
                  float* __restrict__ sc) {
    int bh = blockIdx.x;
    int b = bh >> 2, h = bh & 3;
    int tid = threadIdx.x;

    int slots[16];
    float mv[16], lv[16];
    float M = -1e30f;
#pragma unroll
    for (int i = 0; i < 16; ++i) {
        slots[i] = (b * 16 + i) * 4 + h;
        mv[i] = pml[slots[i] * 2];
        lv[i] = pml[slots[i] * 2 + 1];
        M = fmaxf(M, mv[i]);
    }
    float L = 0.f, acc = 0.f;
#pragma unroll
    for (int i = 0; i < 16; ++i) {
        float wf = __expf(mv[i] - M);
        L += wf * lv[i];
        acc += wf * p_part[(size_t)slots[i] * 256 + tid];
    }
    float invL = 1.0f / L;
    if (tid == 0) {
        sc[bh * 2] = M;
        sc[bh * 2 + 1] = invL;
    }
    __shared__ float ps[256];
    ps[tid] = acc * invL;
    __syncthreads();

    int d = tid & 63, kr = tid >> 6;
    float a2 = 0.f;
#pragma unroll 8
    for (int k = kr * 64; k < kr * 64 + 64; ++k)
        a2 += ps[k] * Wv[k * HD + h * 64 + d];
    __shared__ float rs[4][64];
    rs[kr][d] = a2;
    __syncthreads();
    if (tid < 64) {
        float o = bv[h * 64 + tid] + rs[0][tid] + rs[1][tid] + rs[2][tid] + rs[3][tid];
        hout[b * HD + h * 64 + tid] = fmaxf(o, 0.f);
    }
}

// ---------------------------------------------------------------------------
// Kernel 4: e-pass (unchanged)
// ---------------------------------------------------------------------------
__global__ __launch_bounds__(256)
void epass_kernel(const float* __restrict__ s,
                  const float* __restrict__ sc,
                  float* __restrict__ e_out) {
    int bid = blockIdx.x;
    int b = bid >> 5, t = bid & 31;
    int n = t * 256 + threadIdx.x;
    float4 ev;
#pragma unroll
    for (int h = 0; h < 4; ++h) {
        float M = sc[(b * 4 + h) * 2];
        float invL = sc[(b * 4 + h) * 2 + 1];
        float sv = s[((size_t)(b * 4 + h)) * N_NODES + n];
        (&ev.x)[h] = __expf(sv - M) * invL;
    }
    *reinterpret_cast<float4*>(e_out + ((size_t)(b * N_NODES + n)) * 4) = ev;
}

extern "C" void kernel_launch(void* const* d_in, const int* in_sizes, int n_in,
                              void* d_out, int out_size, void* d_ws, size_t ws_size,
                              hipStream_t stream) {
    const float* query = (const float*)d_in[0];
    const float* key   = (const float*)d_in[1];
    const float* value = (const float*)d_in[2];
    const float* Wq    = (const float*)d_in[3];
    const float* bq    = (const float*)d_in[4];
    const float* Wv    = (const float*)d_in[5];
    const float* bv    = (const float*)d_in[6];
    const float* avec  = (const float*)d_in[7];
    float* out = (float*)d_out;

    char* ws = (char*)d_ws;
    unsigned short* WqP = (unsigned short*)ws;               // 128 KB
    float* hqb     = (float*)(ws + 131072);                  // 32 KB
    float* s       = (float*)(ws + 163840);                  // 4 MB
    float* pml     = (float*)(ws + 4358144);                 // 16 KB
    float* sc      = (float*)(ws + 4374528);                 // 4 KB
    float* p_part  = (float*)(ws + 4378624);                 // 2 MB
    float* p_part2 = (float*)(ws + 6475776);                 // 2 MB (probe scratch)
    float* pml2    = (float*)(ws + 8572928);                 // 16 KB (probe scratch)

    prep_kernel<<<64, 256, 0, stream>>>(query, Wq, bq, WqP, hqb);
    fused_kernel<<<512, 256, 0, stream>>>(key, value, WqP, hqb, avec, s, p_part, pml);
    final_kernel<<<B_SZ * NUM_HEADS, 256, 0, stream>>>(p_part, pml, Wv, bv, out, sc);
    epass_kernel<<<B_SZ * 32, 0 ? 0 : 256, 0, stream>>>(s, sc, out + B_SZ * HD);
    // Diagnostic probes (5x chunk count, scratch outputs):
    stream_probe<<<512, 256, 0, stream>>>(key, value, p_part2, 160);
    comp_probe<<<512, 256, 0, stream>>>(key, value, WqP, hqb, avec, p_part2, pml2, 160);
}

// Round 18
// 187.418 us; speedup vs baseline: 4.3978x; 4.3978x over previous
//
#include <hip/hip_runtime.h>
#include <hip/hip_bf16.h>

#define NUM_HEADS 4
#define HD 256
#define QD 256
#define VD 256
#define B_SZ 32
#define N_NODES 8192
#define NEG_SLOPE 0.2f
#define CH 16
#define NCH 64
#define KSTRIDE 1040
#define RING 3
#define SLOT (CH * KSTRIDE + CH * 1024)   // 33024 B per ring slot

typedef short bf16x8 __attribute__((ext_vector_type(8)));
typedef float f32x4 __attribute__((ext_vector_type(4)));

static __device__ __forceinline__ unsigned short f2bf(float f) {
    __hip_bfloat16 h = __float2bfloat16(f);
    return *reinterpret_cast<unsigned short*>(&h);
}

static __device__ __forceinline__ void gload_lds16(const float* g, void* l) {
    __builtin_amdgcn_global_load_lds(
        (const __attribute__((address_space(1))) void*)g,
        (__attribute__((address_space(3))) void*)l, 16, 0, 0);
}

// ---------------------------------------------------------------------------
// Kernel 1: prep (unchanged)
// ---------------------------------------------------------------------------
__global__ __launch_bounds__(256)
void prep_kernel(const float* __restrict__ query,
                 const float* __restrict__ Wq,
                 const float* __restrict__ bq,
                 unsigned short* __restrict__ WqP,
                 float* __restrict__ hqb) {
    int blk = blockIdx.x;
    int tid = threadIdx.x;
    if (blk < 32) {
        int b = blk, col = tid;
        float acc = 2.0f * bq[col];
#pragma unroll 16
        for (int k = 0; k < QD; ++k)
            acc += query[b * QD + k] * Wq[k * HD + col];
        hqb[b * HD + col] = acc;
    } else {
        int idx = blk - 32;
        int kstep = idx >> 2, g = idx & 3;
        int col = tid;
        int h = col >> 6, ct = (col >> 4) & 3, col16 = col & 15;
        unsigned short v[8];
#pragma unroll
        for (int j = 0; j < 8; ++j)
            v[j] = f2bf(Wq[(kstep * 32 + g * 8 + j) * HD + col]);
        *reinterpret_cast<uint4*>(
            WqP + kstep * 8192 + h * 2048 + ct * 512 + (g * 16 + col16) * 8) =
            *reinterpret_cast<uint4*>(v);
    }
}

// ---------------------------------------------------------------------------
// Kernel 2 (FUSED, producer/consumer decoupled):
// grid 256 = (b, 1024-row strip), 512 thr, 1 block/CU (~99 KB LDS).
// Waves 0-3: PRODUCERS — stream 16-row chunks (key+value) into a 3-slot LDS
//   ring via gload_lds, 16 loads outstanding, flag via LDS atomics.
// Waves 4-7: CONSUMERS (head h=w-4) — R15 compute verbatim per chunk from
//   the ring; online softmax; per-wave p_part slot at end.
// NO block barriers after init -> streaming and compute fully concurrent.
// ---------------------------------------------------------------------------
__global__ __launch_bounds__(512, 2)
void fused_kernel(const float* __restrict__ key,
                  const float* __restrict__ value,
                  const unsigned short* __restrict__ WqP,
                  const float* __restrict__ hqb,
                  const float* __restrict__ avec,
                  float* __restrict__ s,
                  float* __restrict__ p_part,
                  float* __restrict__ pml) {
    __shared__ __align__(16) char smem[RING * SLOT + 64];
    int* flags = reinterpret_cast<int*>(smem + RING * SLOT);
    volatile int* vflags = flags;     // [0..2]=ready, [3..5]=done

    int bid = blockIdx.x;
    int b = bid >> 3, strip = bid & 7;
    int tid = threadIdx.x;
    int w = tid >> 6, lane = tid & 63;
    int rowbase0 = strip * 1024;

    if (tid < 2 * RING) flags[tid] = (tid < RING) ? 0 : 4;
    __syncthreads();                  // flags init visible; ONLY block barrier

    if (w < 4) {
        // ================= PRODUCER wave w: rows w*4..w*4+3 =================
        for (int t = 0; t < NCH; ++t) {
            int sl = t % RING, e = t / RING;
            // wait slot free (consumers done with previous epoch)
            while (vflags[RING + sl] < 4 * e + 4) __builtin_amdgcn_s_sleep(2);
            char* kslot = smem + sl * SLOT;
            char* vslot = kslot + CH * KSTRIDE;
            int rb = rowbase0 + t * CH;
#pragma unroll
            for (int r = 0; r < 4; ++r) {
                int lr_ = w * 4 + r;
                gload_lds16(key + ((size_t)(b * N_NODES + rb + lr_)) * QD + lane * 4,
                            kslot + lr_ * KSTRIDE);
            }
#pragma unroll
            for (int r = 0; r < 4; ++r) {
                int lr_ = w * 4 + r;
                gload_lds16(value + ((size_t)(b * N_NODES + rb + lr_)) * VD + lane * 4,
                            vslot + lr_ * 1024);
            }
            if (t > 0) {
                asm volatile("s_waitcnt vmcnt(8)" ::: "memory");  // chunk t-1 landed
                if (lane == 0) atomicAdd(&flags[(t - 1) % RING], 1);
            }
        }
        asm volatile("s_waitcnt vmcnt(0)" ::: "memory");
        if (lane == 0) atomicAdd(&flags[(NCH - 1) % RING], 1);
    } else {
        // ================= CONSUMER wave: head h = w-4 =================
        int h = w - 4;
        int col16 = lane & 15, g = (lane >> 4) & 3;

        bf16x8 bfr[8][4];
        {
            const unsigned short* wp0 = WqP + h * 2048 + (g * 16 + col16) * 8;
#pragma unroll
            for (int ks = 0; ks < 8; ++ks)
#pragma unroll
                for (int ct = 0; ct < 4; ++ct)
                    bfr[ks][ct] = *reinterpret_cast<const bf16x8*>(wp0 + ks * 8192 + ct * 512);
        }
        float av16[4][4], hq16[4][4];
#pragma unroll
        for (int ct = 0; ct < 4; ++ct)
#pragma unroll
            for (int r = 0; r < 4; ++r) {
                int d = ct * 16 + g * 4 + r;
                av16[ct][r] = avec[d];
                hq16[ct][r] = hqb[b * HD + h * 64 + d];
            }

        float mr = -1e30f, lr = 0.f;
        f32x4 pa = (f32x4){0.f, 0.f, 0.f, 0.f};

        for (int t = 0; t < NCH; ++t) {
            int sl = t % RING, e = t / RING;
            while (vflags[sl] < 4 * (e + 1)) __builtin_amdgcn_s_sleep(2);
            asm volatile("s_waitcnt lgkmcnt(0)" ::: "memory");
            __builtin_amdgcn_sched_barrier(0);

            const char* kb = smem + sl * SLOT;
            const char* vb = kb + CH * KSTRIDE;
            int n0c = rowbase0 + t * CH;

            bf16x8 a[8];
#pragma unroll
            for (int ks = 0; ks < 8; ++ks) {
                f32x4 lo = *reinterpret_cast<const f32x4*>(kb + col16 * KSTRIDE + ks * 128 + g * 32);
                f32x4 hi = *reinterpret_cast<const f32x4*>(kb + col16 * KSTRIDE + ks * 128 + g * 32 + 16);
                unsigned int u0, u1, u2, u3;
                asm("v_cvt_pk_bf16_f32 %0, %1, %2" : "=v"(u0) : "v"(lo[0]), "v"(lo[1]));
                asm("v_cvt_pk_bf16_f32 %0, %1, %2" : "=v"(u1) : "v"(lo[2]), "v"(lo[3]));
                asm("v_cvt_pk_bf16_f32 %0, %1, %2" : "=v"(u2) : "v"(hi[0]), "v"(hi[1]));
                asm("v_cvt_pk_bf16_f32 %0, %1, %2" : "=v"(u3) : "v"(hi[2]), "v"(hi[3]));
                uint4 tt = {u0, u1, u2, u3};
                a[ks] = *reinterpret_cast<bf16x8*>(&tt);
            }

            f32x4 acc[4];
#pragma unroll
            for (int ct = 0; ct < 4; ++ct) acc[ct] = (f32x4){0.f, 0.f, 0.f, 0.f};
#pragma unroll
            for (int ks = 0; ks < 8; ++ks)
#pragma unroll
                for (int ct = 0; ct < 4; ++ct)
                    acc[ct] = __builtin_amdgcn_mfma_f32_16x16x32_bf16(bfr[ks][ct], a[ks], acc[ct], 0, 0, 0);

            float dot = 0.f;
#pragma unroll
            for (int ct = 0; ct < 4; ++ct) {
#pragma unroll
                for (int r = 0; r < 4; ++r) {
                    float pre = acc[ct][r] + hq16[ct][r];
                    float tv = fmaxf(pre, NEG_SLOPE * pre);
                    dot += av16[ct][r] * tv;
                }
            }
            dot += __shfl_xor(dot, 16, 64);
            dot += __shfl_xor(dot, 32, 64);

            if (lane < 16)
                s[((size_t)(b * NUM_HEADS + h)) * N_NODES + n0c + lane] = dot;

            float mc = dot;
            mc = fmaxf(mc, __shfl_xor(mc, 1, 64));
            mc = fmaxf(mc, __shfl_xor(mc, 2, 64));
            mc = fmaxf(mc, __shfl_xor(mc, 4, 64));
            mc = fmaxf(mc, __shfl_xor(mc, 8, 64));
            float mnew = fmaxf(mr, mc);
            float ep = __expf(dot - mnew);
            float lc = ep;
            lc += __shfl_xor(lc, 1, 64);
            lc += __shfl_xor(lc, 2, 64);
            lc += __shfl_xor(lc, 4, 64);
            lc += __shfl_xor(lc, 8, 64);
            float scf = __expf(mr - mnew);
            pa *= scf;
            lr = lr * scf + lc;
            mr = mnew;

#pragma unroll
            for (int n = 0; n < 16; ++n) {
                f32x4 v = *reinterpret_cast<const f32x4*>(vb + n * 1024 + lane * 16);
                float e2 = __shfl(ep, n, 64);
                pa += e2 * v;
            }

            // all my LDS reads of this slot retired -> free it
            asm volatile("s_waitcnt lgkmcnt(0)" ::: "memory");
            if (lane == 0) atomicAdd(&flags[RING + sl], 1);
        }

        int slot = bid * 4 + h;
        *reinterpret_cast<f32x4*>(p_part + (size_t)slot * 256 + lane * 4) = pa;
        if (lane == 0) {
            pml[slot * 2] = mr;
            pml[slot * 2 + 1] = lr;
        }
    }
}

// ---------------------------------------------------------------------------
// Kernel 3: final. Per (b,h): 8 strip-slots; global M,L; rescale-reduce;
// @Wv + bias + relu; emit (M, invL).
// ---------------------------------------------------------------------------
__global__ __launch_bounds__(256)
void final_kernel(const float* __restrict__ p_part,
                  const float* __restrict__ pml,
                  const float* __restrict__ Wv,
                  const float* __restrict__ bv,
                  float* __restrict__ hout,
                  float* __restrict__ sc) {
    int bh = blockIdx.x;
    int b = bh >> 2, h = bh & 3;
    int tid = threadIdx.x;

    int slots[8];
    float mv[8], lv[8];
    float M = -1e30f;
#pragma unroll
    for (int i = 0; i < 8; ++i) {
        slots[i] = (b * 8 + i) * 4 + h;
        mv[i] = pml[slots[i] * 2];
        lv[i] = pml[slots[i] * 2 + 1];
        M = fmaxf(M, mv[i]);
    }
    float L = 0.f, acc = 0.f;
#pragma unroll
    for (int i = 0; i < 8; ++i) {
        float wf = __expf(mv[i] - M);
        L += wf * lv[i];
        acc += wf * p_part[(size_t)slots[i] * 256 + tid];
    }
    float invL = 1.0f / L;
    if (tid == 0) {
        sc[bh * 2] = M;
        sc[bh * 2 + 1] = invL;
    }
    __shared__ float ps[256];
    ps[tid] = acc * invL;
    __syncthreads();

    int d = tid & 63, kr = tid >> 6;
    float a2 = 0.f;
#pragma unroll 8
    for (int k = kr * 64; k < kr * 64 + 64; ++k)
        a2 += ps[k] * Wv[k * HD + h * 64 + d];
    __shared__ float rs[4][64];
    rs[kr][d] = a2;
    __syncthreads();
    if (tid < 64) {
        float o = bv[h * 64 + tid] + rs[0][tid] + rs[1][tid] + rs[2][tid] + rs[3][tid];
        hout[b * HD + h * 64 + tid] = fmaxf(o, 0.f);
    }
}

// ---------------------------------------------------------------------------
// Kernel 4: e-pass (unchanged)
// ---------------------------------------------------------------------------
__global__ __launch_bounds__(256)
void epass_kernel(const float* __restrict__ s,
                  const float* __restrict__ sc,
                  float* __restrict__ e_out) {
    int bid = blockIdx.x;
    int b = bid >> 5, t = bid & 31;
    int n = t * 256 + threadIdx.x;
    float4 ev;
#pragma unroll
    for (int h = 0; h < 4; ++h) {
        float M = sc[(b * 4 + h) * 2];
        float invL = sc[(b * 4 + h) * 2 + 1];
        float sv = s[((size_t)(b * 4 + h)) * N_NODES + n];
        (&ev.x)[h] = __expf(sv - M) * invL;
    }
    *reinterpret_cast<float4*>(e_out + ((size_t)(b * N_NODES + n)) * 4) = ev;
}

extern "C" void kernel_launch(void* const* d_in, const int* in_sizes, int n_in,
                              void* d_out, int out_size, void* d_ws, size_t ws_size,
                              hipStream_t stream) {
    const float* query = (const float*)d_in[0];
    const float* key   = (const float*)d_in[1];
    const float* value = (const float*)d_in[2];
    const float* Wq    = (const float*)d_in[3];
    const float* bq    = (const float*)d_in[4];
    const float* Wv    = (const float*)d_in[5];
    const float* bv    = (const float*)d_in[6];
    const float* avec  = (const float*)d_in[7];
    float* out = (float*)d_out;

    char* ws = (char*)d_ws;
    unsigned short* WqP = (unsigned short*)ws;               // 128 KB
    float* hqb    = (float*)(ws + 131072);                   // 32 KB
    float* s      = (float*)(ws + 163840);                   // 4 MB
    float* pml    = (float*)(ws + 4358144);                  // 32 KB
    float* sc     = (float*)(ws + 4390912);                  // 4 KB
    float* p_part = (float*)(ws + 4395008);                  // 1 MB

    prep_kernel<<<64, 256, 0, stream>>>(query, Wq, bq, WqP, hqb);
    fused_kernel<<<256, 512, 0, stream>>>(key, value, WqP, hqb, avec, s, p_part, pml);
    final_kernel<<<B_SZ * NUM_HEADS, 256, 0, stream>>>(p_part, pml, Wv, bv, out, sc);
    epass_kernel<<<B_SZ * 32, 256, 0, stream>>>(s, sc, out + B_SZ * HD);
}

// Round 19
// 128.185 us; speedup vs baseline: 6.4299x; 1.4621x over previous
//
#include <hip/hip_runtime.h>
#include <hip/hip_bf16.h>

#define NUM_HEADS 4
#define HD 256
#define QD 256
#define VD 256
#define B_SZ 32
#define N_NODES 8192
#define NEG_SLOPE 0.2f
#define CH 32            // rows per chunk
#define NCH 32           // chunks per strip (1024 rows)
#define KSTRIDE 1040     // key LDS row stride bytes

typedef short bf16x8 __attribute__((ext_vector_type(8)));
typedef float f32x4 __attribute__((ext_vector_type(4)));

static __device__ __forceinline__ unsigned short f2bf(float f) {
    __hip_bfloat16 h = __float2bfloat16(f);
    return *reinterpret_cast<unsigned short*>(&h);
}

static __device__ __forceinline__ void gload_lds16(const float* g, void* l) {
    __builtin_amdgcn_global_load_lds(
        (const __attribute__((address_space(1))) void*)g,
        (__attribute__((address_space(3))) void*)l, 16, 0, 0);
}

// ---------------------------------------------------------------------------
// Kernel 1: prep  (hqb + swizzled WqP pack; unchanged)
// ---------------------------------------------------------------------------
__global__ __launch_bounds__(256)
void prep_kernel(const float* __restrict__ query,
                 const float* __restrict__ Wq,
                 const float* __restrict__ bq,
                 unsigned short* __restrict__ WqP,
                 float* __restrict__ hqb) {
    int blk = blockIdx.x;
    int tid = threadIdx.x;
    if (blk < 32) {
        int b = blk, col = tid;
        float acc = 2.0f * bq[col];
#pragma unroll 16
        for (int k = 0; k < QD; ++k)
            acc += query[b * QD + k] * Wq[k * HD + col];
        hqb[b * HD + col] = acc;
    } else {
        int idx = blk - 32;
        int kstep = idx >> 2, g = idx & 3;
        int col = tid;
        int h = col >> 6, ct = (col >> 4) & 3, col16 = col & 15;
        unsigned short v[8];
#pragma unroll
        for (int j = 0; j < 8; ++j)
            v[j] = f2bf(Wq[(kstep * 32 + g * 8 + j) * HD + col]);
        *reinterpret_cast<uint4*>(
            WqP + kstep * 8192 + h * 2048 + ct * 512 + (g * 16 + col16) * 8) =
            *reinterpret_cast<uint4*>(v);
    }
}

// ---------------------------------------------------------------------------
// Kernel 2 (FUSED = R14 + forced pre-loop load resolution + store-aware vmcnt)
// grid 256 = (b, 1024-row strip), 512 thr, 1 block/CU. Wave w: head h=w&3,
// row-half half=w>>2. B-frags persistent in 128 VGPRs; key+value double-
// buffered LDS via gload_lds; swapped-operand MFMA epilogue; online softmax.
//
// R19 changes:
//  (1) dummy-consume bfr/av16/hq16 BEFORE the prologue gloads so the
//      compiler's s_waitcnt for them lands outside the loop (otherwise it
//      re-waits every iteration, draining the in-flight chunk loads = the
//      zero-overlap observed in R13-R17 probes).
//  (2) per-chunk s-store is the 9th-oldest vmcnt op: wait vmcnt(9) (t>0)
//      so we never stall on store acks; t==0 uses vmcnt(8).
// ---------------------------------------------------------------------------
__global__ __launch_bounds__(512, 2)
void fused_kernel(const float* __restrict__ key,
                  const float* __restrict__ value,
                  const unsigned short* __restrict__ WqP,
                  const float* __restrict__ hqb,
                  const float* __restrict__ avec,
                  float* __restrict__ s,
                  float* __restrict__ p_part,
                  float* __restrict__ pml) {
    __shared__ __align__(16) char smem[2 * (CH * KSTRIDE) + 2 * (CH * 1024)];  // 132096 B

    char* kb0 = smem;
    char* kb1 = smem + CH * KSTRIDE;
    char* vb0 = smem + 2 * CH * KSTRIDE;
    char* vb1 = vb0 + CH * 1024;

    int bid = blockIdx.x;
    int b = bid >> 3, strip = bid & 7;
    int tid = threadIdx.x;
    int w = tid >> 6, lane = tid & 63;
    int col16 = lane & 15, g = (lane >> 4) & 3;
    int h = w & 3, half = w >> 2;
    int rowbase0 = strip * 1024;

    // ---- persistent B-fragments for my head: 32 x bf16x8 = 128 VGPRs
    bf16x8 bfr[8][4];
    {
        const unsigned short* wp0 = WqP + h * 2048 + (g * 16 + col16) * 8;
#pragma unroll
        for (int ks = 0; ks < 8; ++ks)
#pragma unroll
            for (int ct = 0; ct < 4; ++ct)
                bfr[ks][ct] = *reinterpret_cast<const bf16x8*>(wp0 + ks * 8192 + ct * 512);
    }
    // per-lane d-constants: d = ct*16 + g*4 + r  (C row mapping, m89)
    float av16[4][4], hq16[4][4];
#pragma unroll
    for (int ct = 0; ct < 4; ++ct)
#pragma unroll
        for (int r = 0; r < 4; ++r) {
            int d = ct * 16 + g * 4 + r;
            av16[ct][r] = avec[d];
            hq16[ct][r] = hqb[b * HD + h * 64 + d];
        }

    // ---- (R19.1) force ALL pre-loop loads resolved HERE, outside the loop.
    // A real use of each value makes the compiler emit its vmcnt/lgkmcnt wait
    // at this point instead of re-waiting inside every loop iteration.
    {
        int dummy = 0;
        float fd = 0.f;
#pragma unroll
        for (int ks = 0; ks < 8; ++ks)
#pragma unroll
            for (int ct = 0; ct < 4; ++ct)
                dummy ^= (int)bfr[ks][ct][0];
#pragma unroll
        for (int ct = 0; ct < 4; ++ct)
#pragma unroll
            for (int r = 0; r < 4; ++r)
                fd += av16[ct][r] + hq16[ct][r];
        asm volatile("" :: "v"(dummy), "v"(fd));
    }

    // ---- running online-softmax state (single head)
    float mr = -1e30f, lr = 0.f;
    f32x4 pa = (f32x4){0.f, 0.f, 0.f, 0.f};

    // ---- prologue: stage chunk 0 (wave w stages rows w*4..w*4+3)
    {
        int rb = rowbase0;
#pragma unroll
        for (int r = 0; r < 4; ++r) {
            int lr_ = w * 4 + r;
            gload_lds16(key + ((size_t)(b * N_NODES + rb + lr_)) * QD + lane * 4,
                        kb0 + lr_ * KSTRIDE);
        }
#pragma unroll
        for (int r = 0; r < 4; ++r) {
            int lr_ = w * 4 + r;
            gload_lds16(value + ((size_t)(b * N_NODES + rb + lr_)) * VD + lane * 4,
                        vb0 + lr_ * 1024);
        }
    }

    for (int t = 0; t < NCH; ++t) {
        __builtin_amdgcn_s_barrier();          // everyone done computing t-1
        if (t + 1 < NCH) {
            char* kbn = ((t + 1) & 1) ? kb1 : kb0;
            char* vbn = ((t + 1) & 1) ? vb1 : vb0;
            int rb = rowbase0 + (t + 1) * CH;
#pragma unroll
            for (int r = 0; r < 4; ++r) {
                int lr_ = w * 4 + r;
                gload_lds16(key + ((size_t)(b * N_NODES + rb + lr_)) * QD + lane * 4,
                            kbn + lr_ * KSTRIDE);
            }
#pragma unroll
            for (int r = 0; r < 4; ++r) {
                int lr_ = w * 4 + r;
                gload_lds16(value + ((size_t)(b * N_NODES + rb + lr_)) * VD + lane * 4,
                            vbn + lr_ * 1024);
            }
            // (R19.2) chunk-t loads are the 8 oldest; the t-1 s-store (if any)
            // is younger than them. t==0: exactly 16 outstanding -> vmcnt(8).
            // t>0: 8(t) + store(t-1) + 8(t+1) -> wait to 9 retires loads(t).
            if (t == 0) asm volatile("s_waitcnt vmcnt(8)" ::: "memory");
            else        asm volatile("s_waitcnt vmcnt(9)" ::: "memory");
        } else {
            asm volatile("s_waitcnt vmcnt(0)" ::: "memory");
        }
        __builtin_amdgcn_s_barrier();          // everyone's chunk-t loads landed
        __builtin_amdgcn_sched_barrier(0);

        const char* kb = (t & 1) ? kb1 : kb0;
        const char* vb = (t & 1) ? vb1 : vb0;
        int n0c = rowbase0 + t * CH;

        // ---- A-side fragments from key LDS (f32 -> bf16); lane&15 = key row
        bf16x8 a[8];
        {
            int krow = half * 16 + col16;
#pragma unroll
            for (int ks = 0; ks < 8; ++ks) {
                f32x4 lo = *reinterpret_cast<const f32x4*>(kb + krow * KSTRIDE + ks * 128 + g * 32);
                f32x4 hi = *reinterpret_cast<const f32x4*>(kb + krow * KSTRIDE + ks * 128 + g * 32 + 16);
                unsigned int u0, u1, u2, u3;
                asm("v_cvt_pk_bf16_f32 %0, %1, %2" : "=v"(u0) : "v"(lo[0]), "v"(lo[1]));
                asm("v_cvt_pk_bf16_f32 %0, %1, %2" : "=v"(u1) : "v"(lo[2]), "v"(lo[3]));
                asm("v_cvt_pk_bf16_f32 %0, %1, %2" : "=v"(u2) : "v"(hi[0]), "v"(hi[1]));
                asm("v_cvt_pk_bf16_f32 %0, %1, %2" : "=v"(u3) : "v"(hi[2]), "v"(hi[3]));
                uint4 tt = {u0, u1, u2, u3};
                a[ks] = *reinterpret_cast<bf16x8*>(&tt);
            }
        }

        // ---- MFMA swapped: C[d][keyrow] = sum_k Wq[k][d]*key[keyrow][k]
        f32x4 acc[4];
#pragma unroll
        for (int ct = 0; ct < 4; ++ct) acc[ct] = (f32x4){0.f, 0.f, 0.f, 0.f};
#pragma unroll
        for (int ks = 0; ks < 8; ++ks)
#pragma unroll
            for (int ct = 0; ct < 4; ++ct)
                acc[ct] = __builtin_amdgcn_mfma_f32_16x16x32_bf16(bfr[ks][ct], a[ks], acc[ct], 0, 0, 0);

        // ---- epilogue: leaky + a-dot over d (regs) + 2 shfl over d-groups
        float dot = 0.f;
#pragma unroll
        for (int ct = 0; ct < 4; ++ct) {
#pragma unroll
            for (int r = 0; r < 4; ++r) {
                float pre = acc[ct][r] + hq16[ct][r];
                float tv = fmaxf(pre, NEG_SLOPE * pre);
                dot += av16[ct][r] * tv;
            }
        }
        dot += __shfl_xor(dot, 16, 64);
        dot += __shfl_xor(dot, 32, 64);
        // dot = full score for key row col16 (dup across the 4 d-groups)

        if (lane < 16) {
            s[((size_t)(b * NUM_HEADS + h)) * N_NODES + n0c + half * 16 + lane] = dot;
        }

        // ---- online softmax over my 16 rows (reduce over col16 group)
        float mc = dot;
        mc = fmaxf(mc, __shfl_xor(mc, 1, 64));
        mc = fmaxf(mc, __shfl_xor(mc, 2, 64));
        mc = fmaxf(mc, __shfl_xor(mc, 4, 64));
        mc = fmaxf(mc, __shfl_xor(mc, 8, 64));
        float mnew = fmaxf(mr, mc);
        float ep = __expf(dot - mnew);
        float lc = ep;
        lc += __shfl_xor(lc, 1, 64);
        lc += __shfl_xor(lc, 2, 64);
        lc += __shfl_xor(lc, 4, 64);
        lc += __shfl_xor(lc, 8, 64);
        float scf = __expf(mr - mnew);
        pa *= scf;
        lr = lr * scf + lc;
        mr = mnew;

        // ---- PV: my half's 16 value rows from LDS, e broadcast via shfl
#pragma unroll
        for (int n = 0; n < 16; ++n) {
            f32x4 v = *reinterpret_cast<const f32x4*>(vb + (half * 16 + n) * 1024 + lane * 16);
            float e = __shfl(ep, n, 64);
            pa += e * v;
        }
    }

    // ---- per-wave output slot
    int slot = bid * 8 + w;
    *reinterpret_cast<f32x4*>(p_part + (size_t)slot * 256 + lane * 4) = pa;
    if (lane == 0) {
        pml[slot * 2] = mr;
        pml[slot * 2 + 1] = lr;
    }
}

// ---------------------------------------------------------------------------
// Kernel 3: final. Per (b,h): 16 slots (8 strips x 2 halves); global M,L;
// rescale-reduce; @Wv + bias + relu; emit (M, invL).
// ---------------------------------------------------------------------------
__global__ __launch_bounds__(256)
void final_kernel(const float* __restrict__ p_part,
                  const float* __restrict__ pml,
                  const float* __restrict__ Wv,
                  const float* __restrict__ bv,
                  float* __restrict__ hout,
                  float* __restrict__ sc) {
    int bh = blockIdx.x;
    int b = bh >> 2, h = bh & 3;
    int tid = threadIdx.x;

    int slots[16];
    float mv[16], lv[16];
    float M = -1e30f;
#pragma unroll
    for (int i = 0; i < 16; ++i) {
        int strip = i >> 1, hf = i & 1;
        slots[i] = (b * 8 + strip) * 8 + hf * 4 + h;
        mv[i] = pml[slots[i] * 2];
        lv[i] = pml[slots[i] * 2 + 1];
        M = fmaxf(M, mv[i]);
    }
    float L = 0.f, acc = 0.f;
#pragma unroll
    for (int i = 0; i < 16; ++i) {
        float wf = __expf(mv[i] - M);
        L += wf * lv[i];
        acc += wf * p_part[(size_t)slots[i] * 256 + tid];
    }
    float invL = 1.0f / L;
    if (tid == 0) {
        sc[bh * 2] = M;
        sc[bh * 2 + 1] = invL;
    }
    __shared__ float ps[256];
    ps[tid] = acc * invL;
    __syncthreads();

    int d = tid & 63, kr = tid >> 6;
    float a2 = 0.f;
#pragma unroll 8
    for (int k = kr * 64; k < kr * 64 + 64; ++k)
        a2 += ps[k] * Wv[k * HD + h * 64 + d];
    __shared__ float rs[4][64];
    rs[kr][d] = a2;
    __syncthreads();
    if (tid < 64) {
        float o = bv[h * 64 + tid] + rs[0][tid] + rs[1][tid] + rs[2][tid] + rs[3][tid];
        hout[b * HD + h * 64 + tid] = fmaxf(o, 0.f);
    }
}

// ---------------------------------------------------------------------------
// Kernel 4: e-pass. e_out[b,n,h] = exp(s[b,h,n]-M)*invL.
// ---------------------------------------------------------------------------
__global__ __launch_bounds__(256)
void epass_kernel(const float* __restrict__ s,
                  const float* __restrict__ sc,
                  float* __restrict__ e_out) {
    int bid = blockIdx.x;
    int b = bid >> 5, t = bid & 31;
    int n = t * 256 + threadIdx.x;
    float4 ev;
#pragma unroll
    for (int h = 0; h < 4; ++h) {
        float M = sc[(b * 4 + h) * 2];
        float invL = sc[(b * 4 + h) * 2 + 1];
        float sv = s[((size_t)(b * 4 + h)) * N_NODES + n];
        (&ev.x)[h] = __expf(sv - M) * invL;
    }
    *reinterpret_cast<float4*>(e_out + ((size_t)(b * N_NODES + n)) * 4) = ev;
}

extern "C" void kernel_launch(void* const* d_in, const int* in_sizes, int n_in,
                              void* d_out, int out_size, void* d_ws, size_t ws_size,
                              hipStream_t stream) {
    const float* query = (const float*)d_in[0];
    const float* key   = (const float*)d_in[1];
    const float* value = (const float*)d_in[2];
    const float* Wq    = (const float*)d_in[3];
    const float* bq    = (const float*)d_in[4];
    const float* Wv    = (const float*)d_in[5];
    const float* bv    = (const float*)d_in[6];
    const float* avec  = (const float*)d_in[7];
    float* out = (float*)d_out;

    char* ws = (char*)d_ws;
    unsigned short* WqP = (unsigned short*)ws;               // 128 KB
    float* hqb    = (float*)(ws + 131072);                   // 32 KB
    float* s      = (float*)(ws + 163840);                   // 4 MB
    float* pml    = (float*)(ws + 4358144);                  // 16 KB
    float* sc     = (float*)(ws + 4374528);                  // 4 KB
    float* p_part = (float*)(ws + 4378624);                  // 2 MB

    prep_kernel<<<64, 256, 0, stream>>>(query, Wq, bq, WqP, hqb);
    fused_kernel<<<256, 512, 0, stream>>>(key, value, WqP, hqb, avec, s, p_part, pml);
    final_kernel<<<B_SZ * NUM_HEADS, 256, 0, stream>>>(p_part, pml, Wv, bv, out, sc);
    epass_kernel<<<B_SZ * 32, 256, 0, stream>>>(s, sc, out + B_SZ * HD);
}